// Round 8
// baseline (222.552 us; speedup 1.0000x reference)
//
#include <hip/hip_runtime.h>
#include <math.h>

#define B_   8
#define CIN  768
#define HID  128
#define NA   36
#define PP   1024

typedef _Float16 f16;
typedef __attribute__((ext_vector_type(2))) _Float16 f16x2;
typedef __attribute__((ext_vector_type(4))) _Float16 f16x4;
typedef __attribute__((ext_vector_type(8))) _Float16 f16x8;
typedef __attribute__((ext_vector_type(4))) float f32x4;
typedef __attribute__((ext_vector_type(4))) unsigned short us4;

#define MFMA16(a, b, c) __builtin_amdgcn_mfma_f32_16x16x32_f16((a), (b), (c), 0, 0, 0)

__device__ inline f16x2 pkrtz(float a, float b) {
  union { __fp16 __attribute__((ext_vector_type(2))) r; f16x2 h; } u;
  u.r = __builtin_amdgcn_cvt_pkrtz(a, b);
  return u.h;
}

// ------------------------------------------------- rotation corner helper
__device__ inline void rot_corners(float ct, float st, int y, int x,
                                   float w[4], int p[4]) {
  float xn = (2.0f * x + 1.0f) * (1.0f / 32.0f) - 1.0f;
  float yn = (2.0f * y + 1.0f) * (1.0f / 32.0f) - 1.0f;
  float gx = ct * xn - st * yn;
  float gy = st * xn + ct * yn;
  float ix = ((gx + 1.0f) * 32.0f - 1.0f) * 0.5f;
  float iy = ((gy + 1.0f) * 32.0f - 1.0f) * 0.5f;
  float x0f = floorf(ix), y0f = floorf(iy);
  float wx = ix - x0f, wy = iy - y0f;
  int x0 = (int)x0f, y0 = (int)y0f;
  int x1 = x0 + 1, y1 = y0 + 1;
  float vx0 = (x0 >= 0 && x0 < 32) ? 1.0f : 0.0f;
  float vx1 = (x1 >= 0 && x1 < 32) ? 1.0f : 0.0f;
  float vy0 = (y0 >= 0 && y0 < 32) ? 1.0f : 0.0f;
  float vy1 = (y1 >= 0 && y1 < 32) ? 1.0f : 0.0f;
  int cx0 = min(max(x0, 0), 31), cx1 = min(max(x1, 0), 31);
  int cy0 = min(max(y0, 0), 31), cy1 = min(max(y1, 0), 31);
  w[0] = (1.0f - wx) * (1.0f - wy) * vx0 * vy0;  p[0] = (cy0 << 5) + cx0;
  w[1] = wx * (1.0f - wy) * vx1 * vy0;           p[1] = (cy0 << 5) + cx1;
  w[2] = (1.0f - wx) * wy * vx0 * vy1;           p[2] = (cy1 << 5) + cx0;
  w[3] = wx * wy * vx1 * vy1;                    p[3] = (cy1 << 5) + cx1;
}

// -------------------------------------------------------------------- prep
__global__ __launch_bounds__(256) void prep_k(
    const float* __restrict__ Wg, const float* __restrict__ Wq,
    const float* __restrict__ W1, const float* __restrict__ b2,
    f16* __restrict__ Wg_h, f16* __restrict__ Wq_h,
    f16* __restrict__ W1_h, float* __restrict__ out) {
  int idx = blockIdx.x * 256 + threadIdx.x;
  if (idx < B_ * NA) out[idx] = b2[0];
  if (idx < 32768) {
    int e = idx * 8;
    const float* src; f16* dst; int off;
    if (e < 98304)       { src = Wg; dst = Wg_h; off = e; }
    else if (e < 196608) { src = Wq; dst = Wq_h; off = e - 98304; }
    else                 { src = W1; dst = W1_h; off = e - 196608; }
    float4 lo = *(const float4*)(src + off);
    float4 hi = *(const float4*)(src + off + 4);
    f16x8 h;
    h[0] = (f16)lo.x; h[1] = (f16)lo.y; h[2] = (f16)lo.z; h[3] = (f16)lo.w;
    h[4] = (f16)hi.x; h[5] = (f16)hi.y; h[6] = (f16)hi.z; h[7] = (f16)hi.w;
    *(f16x8*)(dst + off) = h;
  }
}

// -------------------------------------------------- fused projection kernel
#define WCH_S 264
#define PS_S  132
#define GN_S  136
__global__ __launch_bounds__(512, 4) void projfused_k(
    const float* __restrict__ gal, const float* __restrict__ qry,
    const f16* __restrict__ Wg_h, const f16* __restrict__ Wq_h,
    const f16* __restrict__ W1_h, const float* __restrict__ b1,
    f16* __restrict__ gout, f16* __restrict__ qout,
    float* __restrict__ baseb1) {
  __shared__ __align__(16) char LDSU[67584];
  f16*   Wch = (f16*)LDSU;            // [128][264]
  float* ps  = (float*)LDSU;          // [4][32][132]
  f16*   Gn  = (f16*)LDSU;            // [32][136]
  f16*   W1l = (f16*)(LDSU + 8704);   // [128][136]

  int pblk = blockIdx.x, b = blockIdx.y, z = blockIdx.z;
  const float* imgB = (z ? qry : gal) + (size_t)b * CIN * PP;
  const f16* Wm = z ? Wq_h : Wg_h;
  f16* dst = z ? qout : gout;
  int tid = threadIdx.x, lane = tid & 63, wv = tid >> 6;
  int q = lane >> 4, lr = lane & 15;
  int kw = wv & 3, mw = wv >> 2;
  int pw = pblk * 32 + mw * 16;

  f32x4 acc[8];
  #pragma unroll
  for (int t = 0; t < 8; t++) acc[t] = (f32x4){0.f, 0.f, 0.f, 0.f};

  int so = tid >> 2, sseg = (tid & 3) * 64;
  const float* ipb = imgB + (size_t)(kw * 64 + q * 8) * PP + pw + lr;

  float fim[2][16];
  #pragma unroll
  for (int t = 0; t < 16; t++)
    fim[0][t] = ipb[(size_t)((t >> 3) * 32 + (t & 7)) * PP];

  #pragma unroll
  for (int c3 = 0; c3 < 3; c3++) {
    int cc = c3 << 8;
    f16x8 w8[8];
    #pragma unroll
    for (int j = 0; j < 8; j++)
      w8[j] = *(const f16x8*)(Wm + so * CIN + cc + sseg + j * 8);
    if (c3 < 2) {
      #pragma unroll
      for (int t = 0; t < 16; t++)
        fim[(c3 + 1) & 1][t] =
            ipb[(size_t)(((c3 + 1) << 8) + (t >> 3) * 32 + (t & 7)) * PP];
    }
    #pragma unroll
    for (int j = 0; j < 8; j++)
      *(f16x8*)&Wch[so * WCH_S + sseg + j * 8] = w8[j];
    __syncthreads();
    #pragma unroll
    for (int ksi = 0; ksi < 2; ksi++) {
      union { f16x8 v; f16x2 h[4]; } bf;
      const float* fp = &fim[c3 & 1][ksi * 8];
      bf.h[0] = pkrtz(fp[0], fp[1]); bf.h[1] = pkrtz(fp[2], fp[3]);
      bf.h[2] = pkrtz(fp[4], fp[5]); bf.h[3] = pkrtz(fp[6], fp[7]);
      int k0 = kw * 64 + ksi * 32;
      #pragma unroll
      for (int og = 0; og < 8; og++) {
        f16x8 af = *(const f16x8*)&Wch[(og * 16 + lr) * WCH_S + k0 + q * 8];
        acc[og] = MFMA16(af, bf.v, acc[og]);
      }
    }
    __syncthreads();
  }

  // ---- phase 2: psum -> LDS, combine, l2 norm, store
  #pragma unroll
  for (int og = 0; og < 8; og++)
    *(f32x4*)&ps[kw * (32 * PS_S) + (mw * 16 + lr) * PS_S + og * 16 + q * 4] = acc[og];
  __syncthreads();
  int pos = tid >> 4, oo = (tid & 15) * 8;
  f32x4 v0s = (f32x4){0.f,0.f,0.f,0.f}, v1s = (f32x4){0.f,0.f,0.f,0.f};
  #pragma unroll
  for (int k = 0; k < 4; k++) {
    v0s += *(const f32x4*)&ps[k * (32 * PS_S) + pos * PS_S + oo];
    v1s += *(const f32x4*)&ps[k * (32 * PS_S) + pos * PS_S + oo + 4];
  }
  float ss = v0s.x*v0s.x + v0s.y*v0s.y + v0s.z*v0s.z + v0s.w*v0s.w
           + v1s.x*v1s.x + v1s.y*v1s.y + v1s.z*v1s.z + v1s.w*v1s.w;
  ss += __shfl_xor(ss, 1); ss += __shfl_xor(ss, 2);
  ss += __shfl_xor(ss, 4); ss += __shfl_xor(ss, 8);
  float inv = 1.0f / fmaxf(sqrtf(ss), 1e-12f);
  f16x8 gn8;
  gn8[0] = (f16)(v0s.x*inv); gn8[1] = (f16)(v0s.y*inv);
  gn8[2] = (f16)(v0s.z*inv); gn8[3] = (f16)(v0s.w*inv);
  gn8[4] = (f16)(v1s.x*inv); gn8[5] = (f16)(v1s.y*inv);
  gn8[6] = (f16)(v1s.z*inv); gn8[7] = (f16)(v1s.w*inv);
  *(f16x8*)(dst + (size_t)((b << 10) + pblk * 32 + pos) * HID + oo) = gn8;

  // ---- phase 3 (gallery only): baseb1 = W1[:,0:128] @ gn + b1
  if (z == 0) {
    __syncthreads();
    *(f16x8*)&Gn[pos * GN_S + oo] = gn8;
    {
      int o = tid >> 2, seg = (tid & 3) * 32;
      #pragma unroll
      for (int j = 0; j < 4; j++)
        *(f16x8*)&W1l[o * GN_S + seg + j * 8] =
            *(const f16x8*)(W1_h + o * 512 + seg + j * 8);
    }
    __syncthreads();
    int nw = wv & 3, mw2 = wv >> 2;
    f32x4 acc2[2];
    acc2[0] = (f32x4){0.f,0.f,0.f,0.f}; acc2[1] = (f32x4){0.f,0.f,0.f,0.f};
    #pragma unroll
    for (int ksj = 0; ksj < 4; ksj++) {
      f16x8 bfv = *(const f16x8*)&Gn[(mw2 * 16 + lr) * GN_S + ksj * 32 + q * 8];
      #pragma unroll
      for (int og2 = 0; og2 < 2; og2++) {
        f16x8 af = *(const f16x8*)&W1l[(nw * 32 + og2 * 16 + lr) * GN_S + ksj * 32 + q * 8];
        acc2[og2] = MFMA16(af, bfv, acc2[og2]);
      }
    }
    #pragma unroll
    for (int og2 = 0; og2 < 2; og2++) {
      int o0 = nw * 32 + og2 * 16 + q * 4;
      float4 bb = *(const float4*)(b1 + o0);
      float4 r;
      r.x = acc2[og2][0] + bb.x; r.y = acc2[og2][1] + bb.y;
      r.z = acc2[og2][2] + bb.z; r.w = acc2[og2][3] + bb.w;
      *(float4*)(baseb1 + (size_t)((b << 10) + pblk * 32 + mw2 * 16 + lr) * HID + o0) = r;
    }
  }
}

// ------------------------------------------------------------------- main
// grid (32 y, 8 b, 6 ag) x 256 thr. LDS trimmed to ~53.4 KB (corner tables
// packed f16/ushort — bit-identical: weights were converted to f16 before
// use anyway) -> 3 blocks/CU (was 2). Dbuf X, 1 barrier/angle, corner
// prefetch, C-init from baseb1.
__global__ __launch_bounds__(256, 3) void main_k(
    const f16* __restrict__ g_h, const f16* __restrict__ q_h,
    const float* __restrict__ baseb1, const f16* __restrict__ W1_h,
    const float* __restrict__ W2, const float* __restrict__ angles,
    float* __restrict__ out) {
  __shared__ f16 Xs[2][32 * 392];                 // 50176 B
  __shared__ f16 wtab[6][32][4];                  // 1536 B
  __shared__ unsigned short ptab[6][32][4];       // 1536 B
  __shared__ float redl[24];
  int y = blockIdx.x, b = blockIdx.y;
  int tid = threadIdx.x;
  int lane = tid & 63, wv = tid >> 6;
  int q = lane >> 4, lr = lane & 15;
  int nq = wv * 32;

  // ---- corner tables: 6 angles x 32 positions, computed once
  if (tid < 192) {
    int it = tid >> 5, pos = tid & 31;
    float th = angles[blockIdx.z * 6 + it] * 0.017453292519943295f;
    float ct = cosf(th), st = sinf(th);
    float w4[4]; int p4[4];
    rot_corners(ct, st, y, pos, w4, p4);
    f16x4 wh;
    wh[0] = (f16)w4[0]; wh[1] = (f16)w4[1];
    wh[2] = (f16)w4[2]; wh[3] = (f16)w4[3];
    *(f16x4*)&wtab[it][pos][0] = wh;
    us4 ph;
    ph[0] = (unsigned short)p4[0]; ph[1] = (unsigned short)p4[1];
    ph[2] = (unsigned short)p4[2]; ph[3] = (unsigned short)p4[3];
    *(us4*)&ptab[it][pos][0] = ph;
  }

  // ---- W1 B-fragments (cols 128..512); compiler may reload from L2 (fine)
  f16x8 bfr[12][2];
  #pragma unroll
  for (int s = 0; s < 12; s++)
    #pragma unroll
    for (int ni = 0; ni < 2; ni++) {
      int o = nq + ni * 16 + lr;
      bfr[s][ni] = *(const f16x8*)(W1_h + o * 512 + 128 + s * 32 + q * 8);
    }

  float w2v[2];
  #pragma unroll
  for (int ni = 0; ni < 2; ni++) w2v[ni] = W2[nq + ni * 16 + lr];

  // ---- base+b1 preloaded as MFMA C-init
  f32x4 binit[2][2];
  #pragma unroll
  for (int mi = 0; mi < 2; mi++)
    #pragma unroll
    for (int ni = 0; ni < 2; ni++)
      #pragma unroll
      for (int r = 0; r < 4; r++) {
        int m = mi * 16 + q * 4 + r;
        binit[mi][ni][r] =
            baseb1[(size_t)((b << 10) + (y << 5) + m) * HID + nq + ni * 16 + lr];
      }

  int bx = tid >> 3, ks = tid & 7;
  const f16* qB = q_h + ((size_t)(b << 10)) * HID + ks * 16;
  const f16* gB = g_h + (size_t)((b << 10) + (y << 5) + bx) * HID + ks * 16;
  f16x8 gg[2] = { *(const f16x8*)gB, *(const f16x8*)(gB + 8) };

  __syncthreads();   // wtab/ptab ready

  // ---- prefetch corners for it=0
  f16x8 u[2][2][4];     // [buf][cg][corner]
  f16x4 wcur, wnxt;
  {
    wcur = *(const f16x4*)&wtab[0][bx][0];
    us4 pt = *(const us4*)&ptab[0][bx][0];
    #pragma unroll
    for (int cg = 0; cg < 2; cg++) {
      u[0][cg][0] = *(const f16x8*)(qB + (int)pt[0] * HID + cg * 8);
      u[0][cg][1] = *(const f16x8*)(qB + (int)pt[1] * HID + cg * 8);
      u[0][cg][2] = *(const f16x8*)(qB + (int)pt[2] * HID + cg * 8);
      u[0][cg][3] = *(const f16x8*)(qB + (int)pt[3] * HID + cg * 8);
    }
  }

  float spart[6];
  #pragma unroll
  for (int it = 0; it < 6; it++) {
    int cur = it & 1;
    f16* Xb = &Xs[cur][0];
    // ---- build X = [qr | g.*qr | |g-qr|] from prefetched registers
    {
      f16x2 wc[4];
      wc[0] = (f16x2){wcur[0], wcur[0]};
      wc[1] = (f16x2){wcur[1], wcur[1]};
      wc[2] = (f16x2){wcur[2], wcur[2]};
      wc[3] = (f16x2){wcur[3], wcur[3]};
      #pragma unroll
      for (int cg = 0; cg < 2; cg++) {
        int c = ks * 16 + cg * 8;
        union U8 { f16x8 v; f16x2 h[4]; } u0, u1, u2, u3, gv, oq, om, oa;
        u0.v = u[cur][cg][0]; u1.v = u[cur][cg][1];
        u2.v = u[cur][cg][2]; u3.v = u[cur][cg][3];
        gv.v = gg[cg];
        #pragma unroll
        for (int i = 0; i < 4; i++) {
          f16x2 qr = u0.h[i] * wc[0] + u1.h[i] * wc[1]
                   + u2.h[i] * wc[2] + u3.h[i] * wc[3];
          f16x2 mm = gv.h[i] * qr;
          union { f16x2 h; unsigned int uu; } dd;
          dd.h = gv.h[i] - qr;
          dd.uu &= 0x7fff7fffu;
          oq.h[i] = qr; om.h[i] = mm; oa.h[i] = dd.h;
        }
        *(f16x8*)&Xb[bx * 392 + c] = oq.v;
        *(f16x8*)&Xb[bx * 392 + 128 + c] = om.v;
        *(f16x8*)&Xb[bx * 392 + 256 + c] = oa.v;
      }
    }
    // ---- prefetch corners for it+1 (in flight during MFMA below)
    if (it < 5) {
      wnxt = *(const f16x4*)&wtab[it + 1][bx][0];
      us4 pt = *(const us4*)&ptab[it + 1][bx][0];
      #pragma unroll
      for (int cg = 0; cg < 2; cg++) {
        u[cur ^ 1][cg][0] = *(const f16x8*)(qB + (int)pt[0] * HID + cg * 8);
        u[cur ^ 1][cg][1] = *(const f16x8*)(qB + (int)pt[1] * HID + cg * 8);
        u[cur ^ 1][cg][2] = *(const f16x8*)(qB + (int)pt[2] * HID + cg * 8);
        u[cur ^ 1][cg][3] = *(const f16x8*)(qB + (int)pt[3] * HID + cg * 8);
      }
    }
    __syncthreads();   // single barrier per angle (dbuf)

    // ---- MFMA: C-init from baseb1, K=384
    f32x4 a00 = binit[0][0], a01 = binit[0][1];
    f32x4 a10 = binit[1][0], a11 = binit[1][1];
    #pragma unroll
    for (int s = 0; s < 12; s++) {
      f16x8 af0 = *(const f16x8*)&Xb[(lr) * 392 + s * 32 + q * 8];
      f16x8 af1 = *(const f16x8*)&Xb[(16 + lr) * 392 + s * 32 + q * 8];
      a00 = MFMA16(af0, bfr[s][0], a00);
      a01 = MFMA16(af0, bfr[s][1], a01);
      a10 = MFMA16(af1, bfr[s][0], a10);
      a11 = MFMA16(af1, bfr[s][1], a11);
    }

    // ---- epilogue: relu . W2
    float sv = 0.f;
    #pragma unroll
    for (int r = 0; r < 4; r++) {
      sv = fmaf(w2v[0], fmaxf(a00[r], 0.f), sv);
      sv = fmaf(w2v[1], fmaxf(a01[r], 0.f), sv);
      sv = fmaf(w2v[0], fmaxf(a10[r], 0.f), sv);
      sv = fmaf(w2v[1], fmaxf(a11[r], 0.f), sv);
    }
    spart[it] = sv;
    wcur = wnxt;
  }

  // ---- one reduction + atomic for all 6 angles
  #pragma unroll
  for (int it = 0; it < 6; it++) {
    float v = spart[it];
    #pragma unroll
    for (int off = 32; off > 0; off >>= 1) v += __shfl_down(v, off, 64);
    if (lane == 0) redl[wv * 6 + it] = v;
  }
  __syncthreads();
  if (tid < 6) {
    float tot = redl[tid] + redl[6 + tid] + redl[12 + tid] + redl[18 + tid];
    atomicAdd(&out[b * NA + blockIdx.z * 6 + tid], tot * (1.0f / 1024.0f));
  }
}

// --------------------------------------------------------------------- launch
extern "C" void kernel_launch(void* const* d_in, const int* in_sizes, int n_in,
                              void* d_out, int out_size, void* d_ws, size_t ws_size,
                              hipStream_t stream) {
  const float* gal = (const float*)d_in[0];
  const float* qry = (const float*)d_in[1];
  const float* Wg  = (const float*)d_in[2];
  const float* Wq  = (const float*)d_in[3];
  const float* W1  = (const float*)d_in[4];
  const float* b1  = (const float*)d_in[5];
  const float* W2  = (const float*)d_in[6];
  const float* b2  = (const float*)d_in[7];
  const float* ang = (const float*)d_in[8];
  float* out = (float*)d_out;
  char* ws = (char*)d_ws;
  f16*   g_h    = (f16*)ws;                              // 2 MB
  f16*   q_h    = (f16*)(ws + (2u << 20));               // 2 MB
  float* baseb1 = (float*)(ws + (4u << 20));             // 4 MB
  f16*   Wg_h   = (f16*)(ws + (8u << 20));               // 192 KB
  f16*   Wq_h   = (f16*)(ws + (8u << 20) + 196608);      // 192 KB
  f16*   W1_h   = (f16*)(ws + (8u << 20) + 393216);      // 128 KB

  hipLaunchKernelGGL(prep_k, dim3(128), dim3(256), 0, stream,
                     Wg, Wq, W1, b2, Wg_h, Wq_h, W1_h, out);
  hipLaunchKernelGGL(projfused_k, dim3(32, 8, 2), dim3(512), 0, stream,
                     gal, qry, Wg_h, Wq_h, W1_h, b1, g_h, q_h, baseb1);
  hipLaunchKernelGGL(main_k, dim3(32, 8, 6), dim3(256), 0, stream,
                     g_h, q_h, baseb1, W1_h, W2, ang, out);
}

// Round 9
// 158.670 us; speedup vs baseline: 1.4026x; 1.4026x over previous
//
#include <hip/hip_runtime.h>
#include <math.h>

#define B_   8
#define CIN  768
#define HID  128
#define NA   36
#define PP   1024

typedef _Float16 f16;
typedef __attribute__((ext_vector_type(2))) _Float16 f16x2;
typedef __attribute__((ext_vector_type(4))) _Float16 f16x4;
typedef __attribute__((ext_vector_type(8))) _Float16 f16x8;
typedef __attribute__((ext_vector_type(4))) float f32x4;
typedef __attribute__((ext_vector_type(4))) unsigned short us4;

#define MFMA16(a, b, c) __builtin_amdgcn_mfma_f32_16x16x32_f16((a), (b), (c), 0, 0, 0)

__device__ inline f16x2 pkrtz(float a, float b) {
  union { __fp16 __attribute__((ext_vector_type(2))) r; f16x2 h; } u;
  u.r = __builtin_amdgcn_cvt_pkrtz(a, b);
  return u.h;
}

// ------------------------------------------------- rotation corner helper
__device__ inline void rot_corners(float ct, float st, int y, int x,
                                   float w[4], int p[4]) {
  float xn = (2.0f * x + 1.0f) * (1.0f / 32.0f) - 1.0f;
  float yn = (2.0f * y + 1.0f) * (1.0f / 32.0f) - 1.0f;
  float gx = ct * xn - st * yn;
  float gy = st * xn + ct * yn;
  float ix = ((gx + 1.0f) * 32.0f - 1.0f) * 0.5f;
  float iy = ((gy + 1.0f) * 32.0f - 1.0f) * 0.5f;
  float x0f = floorf(ix), y0f = floorf(iy);
  float wx = ix - x0f, wy = iy - y0f;
  int x0 = (int)x0f, y0 = (int)y0f;
  int x1 = x0 + 1, y1 = y0 + 1;
  float vx0 = (x0 >= 0 && x0 < 32) ? 1.0f : 0.0f;
  float vx1 = (x1 >= 0 && x1 < 32) ? 1.0f : 0.0f;
  float vy0 = (y0 >= 0 && y0 < 32) ? 1.0f : 0.0f;
  float vy1 = (y1 >= 0 && y1 < 32) ? 1.0f : 0.0f;
  int cx0 = min(max(x0, 0), 31), cx1 = min(max(x1, 0), 31);
  int cy0 = min(max(y0, 0), 31), cy1 = min(max(y1, 0), 31);
  w[0] = (1.0f - wx) * (1.0f - wy) * vx0 * vy0;  p[0] = (cy0 << 5) + cx0;
  w[1] = wx * (1.0f - wy) * vx1 * vy0;           p[1] = (cy0 << 5) + cx1;
  w[2] = (1.0f - wx) * wy * vx0 * vy1;           p[2] = (cy1 << 5) + cx0;
  w[3] = wx * wy * vx1 * vy1;                    p[3] = (cy1 << 5) + cx1;
}

// -------------------------------------------------------------------- prep
__global__ __launch_bounds__(256) void prep_k(
    const float* __restrict__ Wg, const float* __restrict__ Wq,
    const float* __restrict__ W1, const float* __restrict__ b2,
    f16* __restrict__ Wg_h, f16* __restrict__ Wq_h,
    f16* __restrict__ W1_h, float* __restrict__ out) {
  int idx = blockIdx.x * 256 + threadIdx.x;
  if (idx < B_ * NA) out[idx] = b2[0];
  if (idx < 32768) {
    int e = idx * 8;
    const float* src; f16* dst; int off;
    if (e < 98304)       { src = Wg; dst = Wg_h; off = e; }
    else if (e < 196608) { src = Wq; dst = Wq_h; off = e - 98304; }
    else                 { src = W1; dst = W1_h; off = e - 196608; }
    float4 lo = *(const float4*)(src + off);
    float4 hi = *(const float4*)(src + off + 4);
    f16x8 h;
    h[0] = (f16)lo.x; h[1] = (f16)lo.y; h[2] = (f16)lo.z; h[3] = (f16)lo.w;
    h[4] = (f16)hi.x; h[5] = (f16)hi.y; h[6] = (f16)hi.z; h[7] = (f16)hi.w;
    *(f16x8*)(dst + off) = h;
  }
}

// -------------------------------------------------- fused projection kernel
#define WCH_S 264
#define PS_S  132
#define GN_S  136
__global__ __launch_bounds__(512, 4) void projfused_k(
    const float* __restrict__ gal, const float* __restrict__ qry,
    const f16* __restrict__ Wg_h, const f16* __restrict__ Wq_h,
    const f16* __restrict__ W1_h, const float* __restrict__ b1,
    f16* __restrict__ gout, f16* __restrict__ qout,
    float* __restrict__ baseb1) {
  __shared__ __align__(16) char LDSU[67584];
  f16*   Wch = (f16*)LDSU;            // [128][264]
  float* ps  = (float*)LDSU;          // [4][32][132]
  f16*   Gn  = (f16*)LDSU;            // [32][136]
  f16*   W1l = (f16*)(LDSU + 8704);   // [128][136]

  int pblk = blockIdx.x, b = blockIdx.y, z = blockIdx.z;
  const float* imgB = (z ? qry : gal) + (size_t)b * CIN * PP;
  const f16* Wm = z ? Wq_h : Wg_h;
  f16* dst = z ? qout : gout;
  int tid = threadIdx.x, lane = tid & 63, wv = tid >> 6;
  int q = lane >> 4, lr = lane & 15;
  int kw = wv & 3, mw = wv >> 2;
  int pw = pblk * 32 + mw * 16;

  f32x4 acc[8];
  #pragma unroll
  for (int t = 0; t < 8; t++) acc[t] = (f32x4){0.f, 0.f, 0.f, 0.f};

  int so = tid >> 2, sseg = (tid & 3) * 64;
  const float* ipb = imgB + (size_t)(kw * 64 + q * 8) * PP + pw + lr;

  float fim[2][16];
  #pragma unroll
  for (int t = 0; t < 16; t++)
    fim[0][t] = ipb[(size_t)((t >> 3) * 32 + (t & 7)) * PP];

  #pragma unroll
  for (int c3 = 0; c3 < 3; c3++) {
    int cc = c3 << 8;
    f16x8 w8[8];
    #pragma unroll
    for (int j = 0; j < 8; j++)
      w8[j] = *(const f16x8*)(Wm + so * CIN + cc + sseg + j * 8);
    if (c3 < 2) {
      #pragma unroll
      for (int t = 0; t < 16; t++)
        fim[(c3 + 1) & 1][t] =
            ipb[(size_t)(((c3 + 1) << 8) + (t >> 3) * 32 + (t & 7)) * PP];
    }
    #pragma unroll
    for (int j = 0; j < 8; j++)
      *(f16x8*)&Wch[so * WCH_S + sseg + j * 8] = w8[j];
    __syncthreads();
    #pragma unroll
    for (int ksi = 0; ksi < 2; ksi++) {
      union { f16x8 v; f16x2 h[4]; } bf;
      const float* fp = &fim[c3 & 1][ksi * 8];
      bf.h[0] = pkrtz(fp[0], fp[1]); bf.h[1] = pkrtz(fp[2], fp[3]);
      bf.h[2] = pkrtz(fp[4], fp[5]); bf.h[3] = pkrtz(fp[6], fp[7]);
      int k0 = kw * 64 + ksi * 32;
      #pragma unroll
      for (int og = 0; og < 8; og++) {
        f16x8 af = *(const f16x8*)&Wch[(og * 16 + lr) * WCH_S + k0 + q * 8];
        acc[og] = MFMA16(af, bf.v, acc[og]);
      }
    }
    __syncthreads();
  }

  // ---- phase 2: psum -> LDS, combine, l2 norm, store
  #pragma unroll
  for (int og = 0; og < 8; og++)
    *(f32x4*)&ps[kw * (32 * PS_S) + (mw * 16 + lr) * PS_S + og * 16 + q * 4] = acc[og];
  __syncthreads();
  int pos = tid >> 4, oo = (tid & 15) * 8;
  f32x4 v0s = (f32x4){0.f,0.f,0.f,0.f}, v1s = (f32x4){0.f,0.f,0.f,0.f};
  #pragma unroll
  for (int k = 0; k < 4; k++) {
    v0s += *(const f32x4*)&ps[k * (32 * PS_S) + pos * PS_S + oo];
    v1s += *(const f32x4*)&ps[k * (32 * PS_S) + pos * PS_S + oo + 4];
  }
  float ss = v0s.x*v0s.x + v0s.y*v0s.y + v0s.z*v0s.z + v0s.w*v0s.w
           + v1s.x*v1s.x + v1s.y*v1s.y + v1s.z*v1s.z + v1s.w*v1s.w;
  ss += __shfl_xor(ss, 1); ss += __shfl_xor(ss, 2);
  ss += __shfl_xor(ss, 4); ss += __shfl_xor(ss, 8);
  float inv = 1.0f / fmaxf(sqrtf(ss), 1e-12f);
  f16x8 gn8;
  gn8[0] = (f16)(v0s.x*inv); gn8[1] = (f16)(v0s.y*inv);
  gn8[2] = (f16)(v0s.z*inv); gn8[3] = (f16)(v0s.w*inv);
  gn8[4] = (f16)(v1s.x*inv); gn8[5] = (f16)(v1s.y*inv);
  gn8[6] = (f16)(v1s.z*inv); gn8[7] = (f16)(v1s.w*inv);
  *(f16x8*)(dst + (size_t)((b << 10) + pblk * 32 + pos) * HID + oo) = gn8;

  // ---- phase 3 (gallery only): baseb1 = W1[:,0:128] @ gn + b1
  if (z == 0) {
    __syncthreads();
    *(f16x8*)&Gn[pos * GN_S + oo] = gn8;
    {
      int o = tid >> 2, seg = (tid & 3) * 32;
      #pragma unroll
      for (int j = 0; j < 4; j++)
        *(f16x8*)&W1l[o * GN_S + seg + j * 8] =
            *(const f16x8*)(W1_h + o * 512 + seg + j * 8);
    }
    __syncthreads();
    int nw = wv & 3, mw2 = wv >> 2;
    f32x4 acc2[2];
    acc2[0] = (f32x4){0.f,0.f,0.f,0.f}; acc2[1] = (f32x4){0.f,0.f,0.f,0.f};
    #pragma unroll
    for (int ksj = 0; ksj < 4; ksj++) {
      f16x8 bfv = *(const f16x8*)&Gn[(mw2 * 16 + lr) * GN_S + ksj * 32 + q * 8];
      #pragma unroll
      for (int og2 = 0; og2 < 2; og2++) {
        f16x8 af = *(const f16x8*)&W1l[(nw * 32 + og2 * 16 + lr) * GN_S + ksj * 32 + q * 8];
        acc2[og2] = MFMA16(af, bfv, acc2[og2]);
      }
    }
    #pragma unroll
    for (int og2 = 0; og2 < 2; og2++) {
      int o0 = nw * 32 + og2 * 16 + q * 4;
      float4 bb = *(const float4*)(b1 + o0);
      float4 r;
      r.x = acc2[og2][0] + bb.x; r.y = acc2[og2][1] + bb.y;
      r.z = acc2[og2][2] + bb.z; r.w = acc2[og2][3] + bb.w;
      *(float4*)(baseb1 + (size_t)((b << 10) + pblk * 32 + mw2 * 16 + lr) * HID + o0) = r;
    }
  }
}

// ------------------------------------------------------------------- main
// grid (32 y, 8 b, 6 ag) x 256 thr. LDS 53.76 KB (packed f16/ushort corner
// tables) -> 3 blocks/CU BY LDS; __launch_bounds__(256,2) keeps the VGPR cap
// at 256 so nothing spills (round 8's LB(256,3) forced a 170-reg cap ->
// 400 MB of scratch traffic, 2x regression). Compiler lands ~100 VGPR ->
// occupancy is LDS-limited at 3 blocks/CU.
__global__ __launch_bounds__(256, 2) void main_k(
    const f16* __restrict__ g_h, const f16* __restrict__ q_h,
    const float* __restrict__ baseb1, const f16* __restrict__ W1_h,
    const float* __restrict__ W2, const float* __restrict__ angles,
    float* __restrict__ out) {
  __shared__ f16 Xs[2][32 * 392];                 // 50176 B
  __shared__ f16 wtab[6][32][4];                  // 1536 B
  __shared__ unsigned short ptab[6][32][4];       // 1536 B
  __shared__ float redl[24];
  int y = blockIdx.x, b = blockIdx.y;
  int tid = threadIdx.x;
  int lane = tid & 63, wv = tid >> 6;
  int q = lane >> 4, lr = lane & 15;
  int nq = wv * 32;

  // ---- corner tables: 6 angles x 32 positions, computed once
  if (tid < 192) {
    int it = tid >> 5, pos = tid & 31;
    float th = angles[blockIdx.z * 6 + it] * 0.017453292519943295f;
    float ct = cosf(th), st = sinf(th);
    float w4[4]; int p4[4];
    rot_corners(ct, st, y, pos, w4, p4);
    f16x4 wh;
    wh[0] = (f16)w4[0]; wh[1] = (f16)w4[1];
    wh[2] = (f16)w4[2]; wh[3] = (f16)w4[3];
    *(f16x4*)&wtab[it][pos][0] = wh;
    us4 ph;
    ph[0] = (unsigned short)p4[0]; ph[1] = (unsigned short)p4[1];
    ph[2] = (unsigned short)p4[2]; ph[3] = (unsigned short)p4[3];
    *(us4*)&ptab[it][pos][0] = ph;
  }

  // ---- W1 B-fragments (cols 128..512); compiler may reload from L2 (fine)
  f16x8 bfr[12][2];
  #pragma unroll
  for (int s = 0; s < 12; s++)
    #pragma unroll
    for (int ni = 0; ni < 2; ni++) {
      int o = nq + ni * 16 + lr;
      bfr[s][ni] = *(const f16x8*)(W1_h + o * 512 + 128 + s * 32 + q * 8);
    }

  float w2v[2];
  #pragma unroll
  for (int ni = 0; ni < 2; ni++) w2v[ni] = W2[nq + ni * 16 + lr];

  // ---- base+b1 preloaded as MFMA C-init
  f32x4 binit[2][2];
  #pragma unroll
  for (int mi = 0; mi < 2; mi++)
    #pragma unroll
    for (int ni = 0; ni < 2; ni++)
      #pragma unroll
      for (int r = 0; r < 4; r++) {
        int m = mi * 16 + q * 4 + r;
        binit[mi][ni][r] =
            baseb1[(size_t)((b << 10) + (y << 5) + m) * HID + nq + ni * 16 + lr];
      }

  int bx = tid >> 3, ks = tid & 7;
  const f16* qB = q_h + ((size_t)(b << 10)) * HID + ks * 16;
  const f16* gB = g_h + (size_t)((b << 10) + (y << 5) + bx) * HID + ks * 16;
  f16x8 gg[2] = { *(const f16x8*)gB, *(const f16x8*)(gB + 8) };

  __syncthreads();   // wtab/ptab ready

  // ---- prefetch corners for it=0
  f16x8 u[2][2][4];     // [buf][cg][corner]
  f16x4 wcur, wnxt;
  {
    wcur = *(const f16x4*)&wtab[0][bx][0];
    us4 pt = *(const us4*)&ptab[0][bx][0];
    #pragma unroll
    for (int cg = 0; cg < 2; cg++) {
      u[0][cg][0] = *(const f16x8*)(qB + (int)pt[0] * HID + cg * 8);
      u[0][cg][1] = *(const f16x8*)(qB + (int)pt[1] * HID + cg * 8);
      u[0][cg][2] = *(const f16x8*)(qB + (int)pt[2] * HID + cg * 8);
      u[0][cg][3] = *(const f16x8*)(qB + (int)pt[3] * HID + cg * 8);
    }
  }

  float spart[6];
  #pragma unroll
  for (int it = 0; it < 6; it++) {
    int cur = it & 1;
    f16* Xb = &Xs[cur][0];
    // ---- build X = [qr | g.*qr | |g-qr|] from prefetched registers
    {
      f16x2 wc[4];
      wc[0] = (f16x2){wcur[0], wcur[0]};
      wc[1] = (f16x2){wcur[1], wcur[1]};
      wc[2] = (f16x2){wcur[2], wcur[2]};
      wc[3] = (f16x2){wcur[3], wcur[3]};
      #pragma unroll
      for (int cg = 0; cg < 2; cg++) {
        int c = ks * 16 + cg * 8;
        union U8 { f16x8 v; f16x2 h[4]; } u0, u1, u2, u3, gv, oq, om, oa;
        u0.v = u[cur][cg][0]; u1.v = u[cur][cg][1];
        u2.v = u[cur][cg][2]; u3.v = u[cur][cg][3];
        gv.v = gg[cg];
        #pragma unroll
        for (int i = 0; i < 4; i++) {
          f16x2 qr = u0.h[i] * wc[0] + u1.h[i] * wc[1]
                   + u2.h[i] * wc[2] + u3.h[i] * wc[3];
          f16x2 mm = gv.h[i] * qr;
          union { f16x2 h; unsigned int uu; } dd;
          dd.h = gv.h[i] - qr;
          dd.uu &= 0x7fff7fffu;
          oq.h[i] = qr; om.h[i] = mm; oa.h[i] = dd.h;
        }
        *(f16x8*)&Xb[bx * 392 + c] = oq.v;
        *(f16x8*)&Xb[bx * 392 + 128 + c] = om.v;
        *(f16x8*)&Xb[bx * 392 + 256 + c] = oa.v;
      }
    }
    // ---- prefetch corners for it+1 (in flight during MFMA below)
    if (it < 5) {
      wnxt = *(const f16x4*)&wtab[it + 1][bx][0];
      us4 pt = *(const us4*)&ptab[it + 1][bx][0];
      #pragma unroll
      for (int cg = 0; cg < 2; cg++) {
        u[cur ^ 1][cg][0] = *(const f16x8*)(qB + (int)pt[0] * HID + cg * 8);
        u[cur ^ 1][cg][1] = *(const f16x8*)(qB + (int)pt[1] * HID + cg * 8);
        u[cur ^ 1][cg][2] = *(const f16x8*)(qB + (int)pt[2] * HID + cg * 8);
        u[cur ^ 1][cg][3] = *(const f16x8*)(qB + (int)pt[3] * HID + cg * 8);
      }
    }
    __syncthreads();   // single barrier per angle (dbuf)

    // ---- MFMA: C-init from baseb1, K=384
    f32x4 a00 = binit[0][0], a01 = binit[0][1];
    f32x4 a10 = binit[1][0], a11 = binit[1][1];
    #pragma unroll
    for (int s = 0; s < 12; s++) {
      f16x8 af0 = *(const f16x8*)&Xb[(lr) * 392 + s * 32 + q * 8];
      f16x8 af1 = *(const f16x8*)&Xb[(16 + lr) * 392 + s * 32 + q * 8];
      a00 = MFMA16(af0, bfr[s][0], a00);
      a01 = MFMA16(af0, bfr[s][1], a01);
      a10 = MFMA16(af1, bfr[s][0], a10);
      a11 = MFMA16(af1, bfr[s][1], a11);
    }

    // ---- epilogue: relu . W2
    float sv = 0.f;
    #pragma unroll
    for (int r = 0; r < 4; r++) {
      sv = fmaf(w2v[0], fmaxf(a00[r], 0.f), sv);
      sv = fmaf(w2v[1], fmaxf(a01[r], 0.f), sv);
      sv = fmaf(w2v[0], fmaxf(a10[r], 0.f), sv);
      sv = fmaf(w2v[1], fmaxf(a11[r], 0.f), sv);
    }
    spart[it] = sv;
    wcur = wnxt;
  }

  // ---- one reduction + atomic for all 6 angles
  #pragma unroll
  for (int it = 0; it < 6; it++) {
    float v = spart[it];
    #pragma unroll
    for (int off = 32; off > 0; off >>= 1) v += __shfl_down(v, off, 64);
    if (lane == 0) redl[wv * 6 + it] = v;
  }
  __syncthreads();
  if (tid < 6) {
    float tot = redl[tid] + redl[6 + tid] + redl[12 + tid] + redl[18 + tid];
    atomicAdd(&out[b * NA + blockIdx.z * 6 + tid], tot * (1.0f / 1024.0f));
  }
}

// --------------------------------------------------------------------- launch
extern "C" void kernel_launch(void* const* d_in, const int* in_sizes, int n_in,
                              void* d_out, int out_size, void* d_ws, size_t ws_size,
                              hipStream_t stream) {
  const float* gal = (const float*)d_in[0];
  const float* qry = (const float*)d_in[1];
  const float* Wg  = (const float*)d_in[2];
  const float* Wq  = (const float*)d_in[3];
  const float* W1  = (const float*)d_in[4];
  const float* b1  = (const float*)d_in[5];
  const float* W2  = (const float*)d_in[6];
  const float* b2  = (const float*)d_in[7];
  const float* ang = (const float*)d_in[8];
  float* out = (float*)d_out;
  char* ws = (char*)d_ws;
  f16*   g_h    = (f16*)ws;                              // 2 MB
  f16*   q_h    = (f16*)(ws + (2u << 20));               // 2 MB
  float* baseb1 = (float*)(ws + (4u << 20));             // 4 MB
  f16*   Wg_h   = (f16*)(ws + (8u << 20));               // 192 KB
  f16*   Wq_h   = (f16*)(ws + (8u << 20) + 196608);      // 192 KB
  f16*   W1_h   = (f16*)(ws + (8u << 20) + 393216);      // 128 KB

  hipLaunchKernelGGL(prep_k, dim3(128), dim3(256), 0, stream,
                     Wg, Wq, W1, b2, Wg_h, Wq_h, W1_h, out);
  hipLaunchKernelGGL(projfused_k, dim3(32, 8, 2), dim3(512), 0, stream,
                     gal, qry, Wg_h, Wq_h, W1_h, b1, g_h, q_h, baseb1);
  hipLaunchKernelGGL(main_k, dim3(32, 8, 6), dim3(256), 0, stream,
                     g_h, q_h, baseb1, W1_h, W2, ang, out);
}